// Round 1
// baseline (436.972 us; speedup 1.0000x reference)
//
#include <hip/hip_runtime.h>

#define B_  16
#define L_  4096
#define D_  512
#define C_  64
#define NC_ 64   // L_/C_

// ---------------------------------------------------------------------------
// filtfilt of one SOS section:
//   forward:  y[t] = bx[t] + A00*y[t-1] + A01*y[t-2],  y[-1]=y[-2]=bx[0]
//             bx[t] = b0*x[t] + b1*x[t-1] + b2*x[t-2]  (replicate x[0] pad)
//   backward: y'[t] = bx'[t] + A00*y'[t+1] + A01*y'[t+2], y'[L]=y'[L+1]=bx'[L-1]
//             bx'[t] = b0*f[t] + b1*f[t+1] + b2*f[t+2]  (replicate f[L-1] pad)
// Chunked linear-recurrence: per chunk, s_out = A^C * s_in + p (zero-state).
// ---------------------------------------------------------------------------

__device__ __forceinline__ void pow_M(float A00, float A01,
                                      float& m00, float& m01,
                                      float& m10, float& m11) {
  // M = A^64 via 6 squarings, A = [[A00,A01],[1,0]]
  m00 = A00; m01 = A01; m10 = 1.f; m11 = 0.f;
#pragma unroll
  for (int it = 0; it < 6; ++it) {
    float n00 = m00 * m00 + m01 * m10;
    float n01 = m00 * m01 + m01 * m11;
    float n10 = m10 * m00 + m11 * m10;
    float n11 = m10 * m01 + m11 * m11;
    m00 = n00; m01 = n01; m10 = n10; m11 = n11;
  }
}

// K1: forward zero-state particular per chunk: p_i = (y_zs[C-1], y_zs[C-2])
__global__ __launch_bounds__(256) void k_fwd_part(const float* __restrict__ x,
                                                  const float* __restrict__ bc,
                                                  const float* __restrict__ am,
                                                  float* __restrict__ p) {
  int g = blockIdx.x * 256 + threadIdx.x;
  int d = g % D_;
  int i = (g / D_) % NC_;
  int b = g / (D_ * NC_);
  float b0 = bc[0], b1 = bc[1], b2 = bc[2];
  float A00 = am[0], A01 = am[1];
  const float* xb = x + (size_t)b * L_ * D_ + d;
  int l0 = i * C_;
  float xm1, xm2;
  if (i == 0) {
    xm1 = xm2 = xb[0];
  } else {
    xm1 = xb[(size_t)(l0 - 1) * D_];
    xm2 = xb[(size_t)(l0 - 2) * D_];
  }
  float y1 = 0.f, y2 = 0.f;
#pragma unroll
  for (int t = 0; t < C_; ++t) {
    float cur = xb[(size_t)(l0 + t) * D_];
    float bx = b0 * cur + b1 * xm1 + b2 * xm2;
    float y = bx + A00 * y1 + A01 * y2;
    xm2 = xm1; xm1 = cur;
    y2 = y1; y1 = y;
  }
  float* pp = p + (size_t)(b * NC_ + i) * 2 * D_ + d;
  pp[0]  = y1;   // y_zs[C-1]
  pp[D_] = y2;   // y_zs[C-2]
}

// K2: forward chunk-state scan: sf_0 = (bx0,bx0); sf_{i+1} = M*sf_i + p_i
__global__ __launch_bounds__(256) void k_fwd_scan(const float* __restrict__ x,
                                                  const float* __restrict__ bc,
                                                  const float* __restrict__ am,
                                                  const float* __restrict__ p,
                                                  float* __restrict__ sf) {
  int g = blockIdx.x * 256 + threadIdx.x;  // B_*D_ threads
  int d = g % D_;
  int b = g / D_;
  float b0 = bc[0], b1 = bc[1], b2 = bc[2];
  float A00 = am[0], A01 = am[1];
  float m00, m01, m10, m11;
  pow_M(A00, A01, m00, m01, m10, m11);

  float x0 = x[(size_t)b * L_ * D_ + d];
  float bx0 = (b0 + b1 + b2) * x0;
  float s0 = bx0, s1 = bx0;  // (y[-1], y[-2])
  const float* pp = p + (size_t)b * NC_ * 2 * D_ + d;
  float* sfp = sf + (size_t)b * (NC_ + 1) * 2 * D_ + d;
  sfp[0] = s0;
  sfp[D_] = s1;
  for (int i = 0; i < NC_; ++i) {
    float p0 = pp[(size_t)i * 2 * D_];
    float p1 = pp[(size_t)i * 2 * D_ + D_];
    float n0 = m00 * s0 + m01 * s1 + p0;
    float n1 = m10 * s0 + m11 * s1 + p1;
    s0 = n0; s1 = n1;
    sfp[(size_t)(i + 1) * 2 * D_]      = s0;
    sfp[(size_t)(i + 1) * 2 * D_ + D_] = s1;
  }
}

// K3: recompute forward chunk from sf_i, then backward zero-state particular
//     q_i = (y'_zs[iC], y'_zs[iC+1])
__global__ __launch_bounds__(256) void k_bwd_part(const float* __restrict__ x,
                                                  const float* __restrict__ bc,
                                                  const float* __restrict__ am,
                                                  const float* __restrict__ sf,
                                                  float* __restrict__ q) {
  int g = blockIdx.x * 256 + threadIdx.x;
  int d = g % D_;
  int i = (g / D_) % NC_;
  int b = g / (D_ * NC_);
  float b0 = bc[0], b1 = bc[1], b2 = bc[2];
  float A00 = am[0], A01 = am[1];
  const float* xb = x + (size_t)b * L_ * D_ + d;
  const float* sfp = sf + (size_t)b * (NC_ + 1) * 2 * D_ + (size_t)i * 2 * D_ + d;
  float y1 = sfp[0];   // y[iC-1]
  float y2 = sfp[D_];  // y[iC-2]
  int l0 = i * C_;
  float xm1, xm2;
  if (i == 0) {
    xm1 = xm2 = xb[0];
  } else {
    xm1 = xb[(size_t)(l0 - 1) * D_];
    xm2 = xb[(size_t)(l0 - 2) * D_];
  }
  float f[C_];
#pragma unroll
  for (int t = 0; t < C_; ++t) {
    float cur = xb[(size_t)(l0 + t) * D_];
    float bx = b0 * cur + b1 * xm1 + b2 * xm2;
    float y = bx + A00 * y1 + A01 * y2;
    f[t] = y;
    xm2 = xm1; xm1 = cur;
    y2 = y1; y1 = y;
  }
  float fe0, fe1;
  if (i < NC_ - 1) {  // extend 2 steps into next chunk (real f values)
    float cur = xb[(size_t)(l0 + C_) * D_];
    float bx = b0 * cur + b1 * xm1 + b2 * xm2;
    fe0 = bx + A00 * y1 + A01 * y2;
    xm2 = xm1; xm1 = cur; y2 = y1; y1 = fe0;
    cur = xb[(size_t)(l0 + C_ + 1) * D_];
    bx = b0 * cur + b1 * xm1 + b2 * xm2;
    fe1 = bx + A00 * y1 + A01 * y2;
  } else {  // replicate pad at sequence end
    fe0 = f[C_ - 1];
    fe1 = f[C_ - 1];
  }
  // backward zero-state over the chunk
  float z1 = 0.f, z2 = 0.f;
#pragma unroll
  for (int t = C_ - 1; t >= 0; --t) {
    float fp1 = (t == C_ - 1) ? fe0 : f[t + 1];
    float fp2 = (t == C_ - 1) ? fe1 : ((t == C_ - 2) ? fe0 : f[t + 2]);
    float bxb = b0 * f[t] + b1 * fp1 + b2 * fp2;
    float z = bxb + A00 * z1 + A01 * z2;
    z2 = z1; z1 = z;
  }
  float* qp = q + (size_t)(b * NC_ + i) * 2 * D_ + d;
  qp[0]  = z1;  // y'_zs[iC]
  qp[D_] = z2;  // y'_zs[iC+1]
}

// K4: backward chunk-state scan: sb_{NC-1} = (c,c), sb_{i-1} = M*sb_i + q_i
__global__ __launch_bounds__(256) void k_bwd_scan(const float* __restrict__ bc,
                                                  const float* __restrict__ am,
                                                  const float* __restrict__ sf,
                                                  const float* __restrict__ q,
                                                  float* __restrict__ sb) {
  int g = blockIdx.x * 256 + threadIdx.x;  // B_*D_ threads
  int d = g % D_;
  int b = g / D_;
  float b0 = bc[0], b1 = bc[1], b2 = bc[2];
  float A00 = am[0], A01 = am[1];
  float m00, m01, m10, m11;
  pow_M(A00, A01, m00, m01, m10, m11);

  float fL1 = sf[(size_t)b * (NC_ + 1) * 2 * D_ + (size_t)NC_ * 2 * D_ + d];  // y[L-1]
  float c = (b0 + b1 + b2) * fL1;  // bx'[L-1]
  float s0 = c, s1 = c;            // (y'[L], y'[L+1])
  const float* qp = q + (size_t)b * NC_ * 2 * D_ + d;
  float* sbp = sb + (size_t)b * NC_ * 2 * D_ + d;
  sbp[(size_t)(NC_ - 1) * 2 * D_]      = s0;
  sbp[(size_t)(NC_ - 1) * 2 * D_ + D_] = s1;
  for (int i = NC_ - 1; i >= 1; --i) {
    float q0 = qp[(size_t)i * 2 * D_];
    float q1 = qp[(size_t)i * 2 * D_ + D_];
    float n0 = m00 * s0 + m01 * s1 + q0;
    float n1 = m10 * s0 + m11 * s1 + q1;
    s0 = n0; s1 = n1;
    sbp[(size_t)(i - 1) * 2 * D_]      = s0;
    sbp[(size_t)(i - 1) * 2 * D_ + D_] = s1;
  }
}

// K5: recompute forward chunk, run backward pass seeded by sb_i, emit outputs
__global__ __launch_bounds__(256) void k_final(const float* __restrict__ x,
                                               const float* __restrict__ bc,
                                               const float* __restrict__ am,
                                               const float* __restrict__ sf,
                                               const float* __restrict__ sb,
                                               float* __restrict__ seas,
                                               float* __restrict__ trend) {
  int g = blockIdx.x * 256 + threadIdx.x;
  int d = g % D_;
  int i = (g / D_) % NC_;
  int b = g / (D_ * NC_);
  float b0 = bc[0], b1 = bc[1], b2 = bc[2];
  float A00 = am[0], A01 = am[1];
  const float* xb = x + (size_t)b * L_ * D_ + d;
  const float* sfp = sf + (size_t)b * (NC_ + 1) * 2 * D_ + (size_t)i * 2 * D_ + d;
  float y1 = sfp[0];
  float y2 = sfp[D_];
  int l0 = i * C_;
  float xm1, xm2;
  if (i == 0) {
    xm1 = xm2 = xb[0];
  } else {
    xm1 = xb[(size_t)(l0 - 1) * D_];
    xm2 = xb[(size_t)(l0 - 2) * D_];
  }
  float f[C_];
  float xa[C_];
#pragma unroll
  for (int t = 0; t < C_; ++t) {
    float cur = xb[(size_t)(l0 + t) * D_];
    xa[t] = cur;
    float bx = b0 * cur + b1 * xm1 + b2 * xm2;
    float y = bx + A00 * y1 + A01 * y2;
    f[t] = y;
    xm2 = xm1; xm1 = cur;
    y2 = y1; y1 = y;
  }
  float fe0, fe1;
  if (i < NC_ - 1) {
    float cur = xb[(size_t)(l0 + C_) * D_];
    float bx = b0 * cur + b1 * xm1 + b2 * xm2;
    fe0 = bx + A00 * y1 + A01 * y2;
    xm2 = xm1; xm1 = cur; y2 = y1; y1 = fe0;
    cur = xb[(size_t)(l0 + C_ + 1) * D_];
    bx = b0 * cur + b1 * xm1 + b2 * xm2;
    fe1 = bx + A00 * y1 + A01 * y2;
  } else {
    fe0 = f[C_ - 1];
    fe1 = f[C_ - 1];
  }
  const float* sbp = sb + (size_t)b * NC_ * 2 * D_ + (size_t)i * 2 * D_ + d;
  float z1 = sbp[0];   // y'[(i+1)C]
  float z2 = sbp[D_];  // y'[(i+1)C+1]
  float* sp = seas + (size_t)b * L_ * D_ + d;
  float* tp = trend + (size_t)b * L_ * D_ + d;
#pragma unroll
  for (int t = C_ - 1; t >= 0; --t) {
    float fp1 = (t == C_ - 1) ? fe0 : f[t + 1];
    float fp2 = (t == C_ - 1) ? fe1 : ((t == C_ - 2) ? fe0 : f[t + 2]);
    float bxb = b0 * f[t] + b1 * fp1 + b2 * fp2;
    float yb = bxb + A00 * z1 + A01 * z2;
    size_t o = (size_t)(l0 + t) * D_;
    sp[o] = yb;
    tp[o] = xa[t] - yb;
    z2 = z1; z1 = yb;
  }
}

extern "C" void kernel_launch(void* const* d_in, const int* in_sizes, int n_in,
                              void* d_out, int out_size, void* d_ws, size_t ws_size,
                              hipStream_t stream) {
  const float* x  = (const float*)d_in[0];
  const float* bc = (const float*)d_in[1];
  const float* am = (const float*)d_in[2];
  float* out = (float*)d_out;
  float* seas  = out;
  float* trend = out + (size_t)B_ * L_ * D_;

  float* ws = (float*)d_ws;
  size_t PN  = (size_t)B_ * NC_ * 2 * D_;        // 1,048,576 floats
  size_t SFN = (size_t)B_ * (NC_ + 1) * 2 * D_;  // 1,064,960 floats
  float* p  = ws;
  float* sf = p + PN;
  float* q  = sf + SFN;
  float* sb = q + PN;
  // total ws: ~16.8 MB

  dim3 blk(256);
  int big_grid   = B_ * NC_ * D_ / 256;  // 2048 blocks
  int small_grid = B_ * D_ / 256;        // 32 blocks

  k_fwd_part<<<big_grid, blk, 0, stream>>>(x, bc, am, p);
  k_fwd_scan<<<small_grid, blk, 0, stream>>>(x, bc, am, p, sf);
  k_bwd_part<<<big_grid, blk, 0, stream>>>(x, bc, am, sf, q);
  k_bwd_scan<<<small_grid, blk, 0, stream>>>(bc, am, sf, q, sb);
  k_final<<<big_grid, blk, 0, stream>>>(x, bc, am, sf, sb, seas, trend);
}

// Round 2
// 426.154 us; speedup vs baseline: 1.0254x; 1.0254x over previous
//
#include <hip/hip_runtime.h>

#define B_   16
#define L_   4096
#define D_   512
#define C_   32
#define NC_  128   // L_/C_
#define LOG2C_ 5

// ---------------------------------------------------------------------------
// filtfilt of one SOS section:
//   forward:  y[t] = bx[t] + A00*y[t-1] + A01*y[t-2],  y[-1]=y[-2]=bx[0]
//             bx[t] = b0*x[t] + b1*x[t-1] + b2*x[t-2]  (replicate x[0] pad)
//   backward: y'[t] = bx'[t] + A00*y'[t+1] + A01*y'[t+2], y'[L]=y'[L+1]=bx'[L-1]
//             bx'[t] = b0*f[t] + b1*f[t+1] + b2*f[t+2]  (replicate f[L-1] pad)
// Chunked linear-recurrence: per chunk, s_out = A^C * s_in + p (zero-state).
// C=32: keeps per-thread arrays (f[32], xa[32]) small enough to avoid VGPR
// spills and keep >=4 waves/SIMD occupancy (R1 at C=64 was ~3x traffic floor,
// suspected spill/occupancy bound).
// ---------------------------------------------------------------------------

__device__ __forceinline__ void pow_M(float A00, float A01,
                                      float& m00, float& m01,
                                      float& m10, float& m11) {
  // M = A^C via LOG2C_ squarings, A = [[A00,A01],[1,0]]
  m00 = A00; m01 = A01; m10 = 1.f; m11 = 0.f;
#pragma unroll
  for (int it = 0; it < LOG2C_; ++it) {
    float n00 = m00 * m00 + m01 * m10;
    float n01 = m00 * m01 + m01 * m11;
    float n10 = m10 * m00 + m11 * m10;
    float n11 = m10 * m01 + m11 * m11;
    m00 = n00; m01 = n01; m10 = n10; m11 = n11;
  }
}

// K1: forward zero-state particular per chunk: p_i = (y_zs[C-1], y_zs[C-2])
__global__ __launch_bounds__(256) void k_fwd_part(const float* __restrict__ x,
                                                  const float* __restrict__ bc,
                                                  const float* __restrict__ am,
                                                  float* __restrict__ p) {
  int g = blockIdx.x * 256 + threadIdx.x;
  int d = g % D_;
  int i = (g / D_) % NC_;
  int b = g / (D_ * NC_);
  float b0 = bc[0], b1 = bc[1], b2 = bc[2];
  float A00 = am[0], A01 = am[1];
  const float* xb = x + (size_t)b * L_ * D_ + d;
  int l0 = i * C_;
  float xm1, xm2;
  if (i == 0) {
    xm1 = xm2 = xb[0];
  } else {
    xm1 = xb[(size_t)(l0 - 1) * D_];
    xm2 = xb[(size_t)(l0 - 2) * D_];
  }
  float y1 = 0.f, y2 = 0.f;
#pragma unroll
  for (int t = 0; t < C_; ++t) {
    float cur = xb[(size_t)(l0 + t) * D_];
    float bx = b0 * cur + b1 * xm1 + b2 * xm2;
    float y = bx + A00 * y1 + A01 * y2;
    xm2 = xm1; xm1 = cur;
    y2 = y1; y1 = y;
  }
  float* pp = p + (size_t)(b * NC_ + i) * 2 * D_ + d;
  pp[0]  = y1;   // y_zs[C-1]
  pp[D_] = y2;   // y_zs[C-2]
}

// K2: forward chunk-state scan: sf_0 = (bx0,bx0); sf_{i+1} = M*sf_i + p_i
__global__ __launch_bounds__(256) void k_fwd_scan(const float* __restrict__ x,
                                                  const float* __restrict__ bc,
                                                  const float* __restrict__ am,
                                                  const float* __restrict__ p,
                                                  float* __restrict__ sf) {
  int g = blockIdx.x * 256 + threadIdx.x;  // B_*D_ threads
  int d = g % D_;
  int b = g / D_;
  float b0 = bc[0], b1 = bc[1], b2 = bc[2];
  float A00 = am[0], A01 = am[1];
  float m00, m01, m10, m11;
  pow_M(A00, A01, m00, m01, m10, m11);

  float x0 = x[(size_t)b * L_ * D_ + d];
  float bx0 = (b0 + b1 + b2) * x0;
  float s0 = bx0, s1 = bx0;  // (y[-1], y[-2])
  const float* pp = p + (size_t)b * NC_ * 2 * D_ + d;
  float* sfp = sf + (size_t)b * (NC_ + 1) * 2 * D_ + d;
  sfp[0] = s0;
  sfp[D_] = s1;
  for (int i = 0; i < NC_; ++i) {
    float p0 = pp[(size_t)i * 2 * D_];
    float p1 = pp[(size_t)i * 2 * D_ + D_];
    float n0 = m00 * s0 + m01 * s1 + p0;
    float n1 = m10 * s0 + m11 * s1 + p1;
    s0 = n0; s1 = n1;
    sfp[(size_t)(i + 1) * 2 * D_]      = s0;
    sfp[(size_t)(i + 1) * 2 * D_ + D_] = s1;
  }
}

// K3: recompute forward chunk from sf_i, then backward zero-state particular
//     q_i = (y'_zs[iC], y'_zs[iC+1])
__global__ __launch_bounds__(256) void k_bwd_part(const float* __restrict__ x,
                                                  const float* __restrict__ bc,
                                                  const float* __restrict__ am,
                                                  const float* __restrict__ sf,
                                                  float* __restrict__ q) {
  int g = blockIdx.x * 256 + threadIdx.x;
  int d = g % D_;
  int i = (g / D_) % NC_;
  int b = g / (D_ * NC_);
  float b0 = bc[0], b1 = bc[1], b2 = bc[2];
  float A00 = am[0], A01 = am[1];
  const float* xb = x + (size_t)b * L_ * D_ + d;
  const float* sfp = sf + (size_t)b * (NC_ + 1) * 2 * D_ + (size_t)i * 2 * D_ + d;
  float y1 = sfp[0];   // y[iC-1]
  float y2 = sfp[D_];  // y[iC-2]
  int l0 = i * C_;
  float xm1, xm2;
  if (i == 0) {
    xm1 = xm2 = xb[0];
  } else {
    xm1 = xb[(size_t)(l0 - 1) * D_];
    xm2 = xb[(size_t)(l0 - 2) * D_];
  }
  float f[C_];
#pragma unroll
  for (int t = 0; t < C_; ++t) {
    float cur = xb[(size_t)(l0 + t) * D_];
    float bx = b0 * cur + b1 * xm1 + b2 * xm2;
    float y = bx + A00 * y1 + A01 * y2;
    f[t] = y;
    xm2 = xm1; xm1 = cur;
    y2 = y1; y1 = y;
  }
  float fe0, fe1;
  if (i < NC_ - 1) {  // extend 2 steps into next chunk (real f values)
    float cur = xb[(size_t)(l0 + C_) * D_];
    float bx = b0 * cur + b1 * xm1 + b2 * xm2;
    fe0 = bx + A00 * y1 + A01 * y2;
    xm2 = xm1; xm1 = cur; y2 = y1; y1 = fe0;
    cur = xb[(size_t)(l0 + C_ + 1) * D_];
    bx = b0 * cur + b1 * xm1 + b2 * xm2;
    fe1 = bx + A00 * y1 + A01 * y2;
  } else {  // replicate pad at sequence end
    fe0 = f[C_ - 1];
    fe1 = f[C_ - 1];
  }
  // backward zero-state over the chunk
  float z1 = 0.f, z2 = 0.f;
#pragma unroll
  for (int t = C_ - 1; t >= 0; --t) {
    float fp1 = (t == C_ - 1) ? fe0 : f[t + 1];
    float fp2 = (t == C_ - 1) ? fe1 : ((t == C_ - 2) ? fe0 : f[t + 2]);
    float bxb = b0 * f[t] + b1 * fp1 + b2 * fp2;
    float z = bxb + A00 * z1 + A01 * z2;
    z2 = z1; z1 = z;
  }
  float* qp = q + (size_t)(b * NC_ + i) * 2 * D_ + d;
  qp[0]  = z1;  // y'_zs[iC]
  qp[D_] = z2;  // y'_zs[iC+1]
}

// K4: backward chunk-state scan: sb_{NC-1} = (c,c), sb_{i-1} = M*sb_i + q_i
__global__ __launch_bounds__(256) void k_bwd_scan(const float* __restrict__ bc,
                                                  const float* __restrict__ am,
                                                  const float* __restrict__ sf,
                                                  const float* __restrict__ q,
                                                  float* __restrict__ sb) {
  int g = blockIdx.x * 256 + threadIdx.x;  // B_*D_ threads
  int d = g % D_;
  int b = g / D_;
  float b0 = bc[0], b1 = bc[1], b2 = bc[2];
  float A00 = am[0], A01 = am[1];
  float m00, m01, m10, m11;
  pow_M(A00, A01, m00, m01, m10, m11);

  float fL1 = sf[(size_t)b * (NC_ + 1) * 2 * D_ + (size_t)NC_ * 2 * D_ + d];  // y[L-1]
  float c = (b0 + b1 + b2) * fL1;  // bx'[L-1]
  float s0 = c, s1 = c;            // (y'[L], y'[L+1])
  const float* qp = q + (size_t)b * NC_ * 2 * D_ + d;
  float* sbp = sb + (size_t)b * NC_ * 2 * D_ + d;
  sbp[(size_t)(NC_ - 1) * 2 * D_]      = s0;
  sbp[(size_t)(NC_ - 1) * 2 * D_ + D_] = s1;
  for (int i = NC_ - 1; i >= 1; --i) {
    float q0 = qp[(size_t)i * 2 * D_];
    float q1 = qp[(size_t)i * 2 * D_ + D_];
    float n0 = m00 * s0 + m01 * s1 + q0;
    float n1 = m10 * s0 + m11 * s1 + q1;
    s0 = n0; s1 = n1;
    sbp[(size_t)(i - 1) * 2 * D_]      = s0;
    sbp[(size_t)(i - 1) * 2 * D_ + D_] = s1;
  }
}

// K5: recompute forward chunk, run backward pass seeded by sb_i, emit outputs
__global__ __launch_bounds__(256) void k_final(const float* __restrict__ x,
                                               const float* __restrict__ bc,
                                               const float* __restrict__ am,
                                               const float* __restrict__ sf,
                                               const float* __restrict__ sb,
                                               float* __restrict__ seas,
                                               float* __restrict__ trend) {
  int g = blockIdx.x * 256 + threadIdx.x;
  int d = g % D_;
  int i = (g / D_) % NC_;
  int b = g / (D_ * NC_);
  float b0 = bc[0], b1 = bc[1], b2 = bc[2];
  float A00 = am[0], A01 = am[1];
  const float* xb = x + (size_t)b * L_ * D_ + d;
  const float* sfp = sf + (size_t)b * (NC_ + 1) * 2 * D_ + (size_t)i * 2 * D_ + d;
  float y1 = sfp[0];
  float y2 = sfp[D_];
  int l0 = i * C_;
  float xm1, xm2;
  if (i == 0) {
    xm1 = xm2 = xb[0];
  } else {
    xm1 = xb[(size_t)(l0 - 1) * D_];
    xm2 = xb[(size_t)(l0 - 2) * D_];
  }
  float f[C_];
  float xa[C_];
#pragma unroll
  for (int t = 0; t < C_; ++t) {
    float cur = xb[(size_t)(l0 + t) * D_];
    xa[t] = cur;
    float bx = b0 * cur + b1 * xm1 + b2 * xm2;
    float y = bx + A00 * y1 + A01 * y2;
    f[t] = y;
    xm2 = xm1; xm1 = cur;
    y2 = y1; y1 = y;
  }
  float fe0, fe1;
  if (i < NC_ - 1) {
    float cur = xb[(size_t)(l0 + C_) * D_];
    float bx = b0 * cur + b1 * xm1 + b2 * xm2;
    fe0 = bx + A00 * y1 + A01 * y2;
    xm2 = xm1; xm1 = cur; y2 = y1; y1 = fe0;
    cur = xb[(size_t)(l0 + C_ + 1) * D_];
    bx = b0 * cur + b1 * xm1 + b2 * xm2;
    fe1 = bx + A00 * y1 + A01 * y2;
  } else {
    fe0 = f[C_ - 1];
    fe1 = f[C_ - 1];
  }
  const float* sbp = sb + (size_t)b * NC_ * 2 * D_ + (size_t)i * 2 * D_ + d;
  float z1 = sbp[0];   // y'[(i+1)C]
  float z2 = sbp[D_];  // y'[(i+1)C+1]
  float* sp = seas + (size_t)b * L_ * D_ + d;
  float* tp = trend + (size_t)b * L_ * D_ + d;
#pragma unroll
  for (int t = C_ - 1; t >= 0; --t) {
    float fp1 = (t == C_ - 1) ? fe0 : f[t + 1];
    float fp2 = (t == C_ - 1) ? fe1 : ((t == C_ - 2) ? fe0 : f[t + 2]);
    float bxb = b0 * f[t] + b1 * fp1 + b2 * fp2;
    float yb = bxb + A00 * z1 + A01 * z2;
    size_t o = (size_t)(l0 + t) * D_;
    // write-once outputs: keep them out of L2 so x reads cache better
    __builtin_nontemporal_store(yb, sp + o);
    __builtin_nontemporal_store(xa[t] - yb, tp + o);
    z2 = z1; z1 = yb;
  }
}

extern "C" void kernel_launch(void* const* d_in, const int* in_sizes, int n_in,
                              void* d_out, int out_size, void* d_ws, size_t ws_size,
                              hipStream_t stream) {
  const float* x  = (const float*)d_in[0];
  const float* bc = (const float*)d_in[1];
  const float* am = (const float*)d_in[2];
  float* out = (float*)d_out;
  float* seas  = out;
  float* trend = out + (size_t)B_ * L_ * D_;

  float* ws = (float*)d_ws;
  size_t PN  = (size_t)B_ * NC_ * 2 * D_;        // 2,097,152 floats
  size_t SFN = (size_t)B_ * (NC_ + 1) * 2 * D_;
  float* p  = ws;
  float* sf = p + PN;
  float* q  = sf + SFN;
  float* sb = q + PN;
  // total ws: ~33.6 MB

  dim3 blk(256);
  int big_grid   = B_ * NC_ * D_ / 256;  // 4096 blocks
  int small_grid = B_ * D_ / 256;        // 32 blocks

  k_fwd_part<<<big_grid, blk, 0, stream>>>(x, bc, am, p);
  k_fwd_scan<<<small_grid, blk, 0, stream>>>(x, bc, am, p, sf);
  k_bwd_part<<<big_grid, blk, 0, stream>>>(x, bc, am, sf, q);
  k_bwd_scan<<<small_grid, blk, 0, stream>>>(bc, am, sf, q, sb);
  k_final<<<big_grid, blk, 0, stream>>>(x, bc, am, sf, sb, seas, trend);
}